// Round 1
// baseline (564.717 us; speedup 1.0000x reference)
//
#include <hip/hip_runtime.h>
#include <cstddef>

// DIN-style attention: per (b,l) MLP score -> masked softmax over L -> weighted sum.
// B=2048, L=200, 2D=128, H1=80, H2=40.
// Key algebra: feats=[q,ub,q-ub,q*ub] =>
//   preact1[l,h] = qt[h] + sum_k ub[l,k]*Wq[k,h]
//   qt[h]  = b1[h] + sum_k q[k]*(W1[k,h] + W1[256+k,h])
//   Wq[k,h]= W1[128+k,h] - W1[256+k,h] + q[k]*W1[384+k,h]
// K drops 512 -> 128 for the dominant GEMM.

#define B_   2048
#define L_   200
#define D2_  128
#define H1_  80
#define H2_  40

#define UB_STRIDE 36   // 32 k-chunk + pad, 16B-aligned rows, 2-way bank alias (free)
#define W2_STRIDE 44   // 40 + pad to break 4-way hq conflict, 16B multiple

__device__ __forceinline__ float f4get(const float4& v, int c) {
  return c == 0 ? v.x : c == 1 ? v.y : c == 2 ? v.z : v.w;
}

__device__ __forceinline__ float sigmoidf_(float x) {
  return 1.0f / (1.0f + __expf(-x));
}

extern "C" __global__ void __launch_bounds__(256, 2)
din_attn_kernel(const float* __restrict__ queries,
                const float* __restrict__ ub,
                const int*   __restrict__ masks,
                const float* __restrict__ w1,
                const float* __restrict__ b1,
                const float* __restrict__ w2,
                const float* __restrict__ b2,
                const float* __restrict__ w3,
                const float* __restrict__ b3,
                float* __restrict__ out)
{
  __shared__ __align__(16) float q_s[128];
  __shared__ __align__(16) float qt_s[H1_];
  __shared__ __align__(16) float w2_s[H1_ * W2_STRIDE];   // 14.1 KB
  __shared__ __align__(16) float b2_s[H2_];
  __shared__ __align__(16) float w3_s[H2_];
  __shared__ float b3_s;
  __shared__ __align__(16) float ubs[L_ * UB_STRIDE];     // 28.8 KB (one 32-wide k chunk)
  __shared__ __align__(16) float wqs[32 * H1_];           // 10.24 KB (Wq chunk; also qt scratch; also out scratch)
  __shared__ __align__(16) float scores_s[256];
  __shared__ float red_s[8];

  const int b    = blockIdx.x;
  const int t    = threadIdx.x;
  const int wave = t >> 6;
  const int lane = t & 63;
  const int li   = lane >> 2;      // 0..15
  const int hq   = lane & 3;       // 0..3
  const int h0   = hq * 20;

  // ---- stage q ----
  if (t < 128) q_s[t] = queries[(size_t)b * D2_ + t];
  __syncthreads();

  // ---- qt partials (use wqs as scratch), stage w2/b2/w3/b3 ----
  if (t < 240) {
    const int h = t % 80, seg = t / 80;
    const int k0 = seg * 43;
    const int k1 = (k0 + 43 < 128) ? (k0 + 43) : 128;
    float acc = 0.0f;
    for (int k = k0; k < k1; ++k)
      acc += q_s[k] * (w1[k * H1_ + h] + w1[(256 + k) * H1_ + h]);
    wqs[seg * 80 + h] = acc;
  }
  #pragma unroll
  for (int i = 0; i < 13; ++i) {
    int idx = i * 256 + t;
    if (idx < H1_ * H2_) w2_s[(idx / 40) * W2_STRIDE + (idx % 40)] = w2[idx];
  }
  if (t < 40) b2_s[t] = b2[t];
  if (t >= 64 && t < 104) w3_s[t - 64] = w3[t - 64];
  if (t == 128) b3_s = b3[0];
  __syncthreads();
  if (t < 80) qt_s[t] = b1[t] + wqs[t] + wqs[80 + t] + wqs[160 + t];
  __syncthreads();

  // ---- row assignment: l = wave*64 + i*16 + li (consecutive-li rows => conflict-free) ----
  int lrow[4], ro[4];
  #pragma unroll
  for (int i = 0; i < 4; ++i) {
    lrow[i] = wave * 64 + i * 16 + li;
    ro[i]   = (lrow[i] < L_ ? lrow[i] : 0) * UB_STRIDE;
  }

  float4 a[4][5];
  #pragma unroll
  for (int i = 0; i < 4; ++i)
    #pragma unroll
    for (int c = 0; c < 5; ++c) a[i][c] = make_float4(0.f, 0.f, 0.f, 0.f);

  // ---- GEMM1: (200x128) @ (128x80), K in 4 chunks of 32 ----
  const float* ubbase = ub + (size_t)b * L_ * D2_;
  for (int kc = 0; kc < 4; ++kc) {
    // stage ub chunk (coalesced 32-float rows)
    const float* ubb = ubbase + kc * 32;
    #pragma unroll
    for (int i = 0; i < 25; ++i) {
      int idx = i * 256 + t;             // < 6400
      int l = idx >> 5, kk = idx & 31;
      ubs[l * UB_STRIDE + kk] = ubb[(size_t)l * D2_ + kk];
    }
    // build Wq chunk (coalesced over h; w1 stays L2-resident)
    #pragma unroll
    for (int i = 0; i < 10; ++i) {
      int idx = i * 256 + t;             // < 2560
      int kk = idx / 80, h = idx - kk * 80;
      int k = kc * 32 + kk;
      wqs[kk * H1_ + h] = w1[(128 + k) * H1_ + h] - w1[(256 + k) * H1_ + h]
                        + q_s[k] * w1[(384 + k) * H1_ + h];
    }
    __syncthreads();

    for (int kk = 0; kk < 32; ++kk) {
      float u0 = ubs[ro[0] + kk];
      float u1 = ubs[ro[1] + kk];
      float u2 = ubs[ro[2] + kk];
      float u3 = ubs[ro[3] + kk];
      const float4* wr = (const float4*)(wqs + kk * H1_ + h0);
      #pragma unroll
      for (int c = 0; c < 5; ++c) {
        float4 wv = wr[c];
        a[0][c].x += u0 * wv.x; a[0][c].y += u0 * wv.y; a[0][c].z += u0 * wv.z; a[0][c].w += u0 * wv.w;
        a[1][c].x += u1 * wv.x; a[1][c].y += u1 * wv.y; a[1][c].z += u1 * wv.z; a[1][c].w += u1 * wv.w;
        a[2][c].x += u2 * wv.x; a[2][c].y += u2 * wv.y; a[2][c].z += u2 * wv.z; a[2][c].w += u2 * wv.w;
        a[3][c].x += u3 * wv.x; a[3][c].y += u3 * wv.y; a[3][c].z += u3 * wv.z; a[3][c].w += u3 * wv.w;
      }
    }
    __syncthreads();
  }

  // ---- layer 2+3 per row: sigmoid -> (1x20)@(20x40) partial -> quad shuffle reduce -> score ----
  #pragma unroll
  for (int i = 0; i < 4; ++i) {
    float4 p[10];
    #pragma unroll
    for (int c = 0; c < 10; ++c) p[c] = make_float4(0.f, 0.f, 0.f, 0.f);
    #pragma unroll
    for (int hh = 0; hh < 20; ++hh) {
      float x  = f4get(a[i][hh >> 2], hh & 3) + qt_s[h0 + hh];
      float hv = sigmoidf_(x);
      const float4* w2r = (const float4*)(w2_s + (h0 + hh) * W2_STRIDE);
      #pragma unroll
      for (int c = 0; c < 10; ++c) {
        float4 wv = w2r[c];
        p[c].x += hv * wv.x; p[c].y += hv * wv.y; p[c].z += hv * wv.z; p[c].w += hv * wv.w;
      }
    }
    // reduce partials across the 4 hq lanes (quad = same li)
    #pragma unroll
    for (int c = 0; c < 10; ++c) {
      p[c].x += __shfl_xor(p[c].x, 1, 64);
      p[c].y += __shfl_xor(p[c].y, 1, 64);
      p[c].z += __shfl_xor(p[c].z, 1, 64);
      p[c].w += __shfl_xor(p[c].w, 1, 64);
      p[c].x += __shfl_xor(p[c].x, 2, 64);
      p[c].y += __shfl_xor(p[c].y, 2, 64);
      p[c].z += __shfl_xor(p[c].z, 2, 64);
      p[c].w += __shfl_xor(p[c].w, 2, 64);
    }
    float score = b3_s;
    #pragma unroll
    for (int j = 0; j < 40; ++j) {
      float x  = f4get(p[j >> 2], j & 3) + b2_s[j];
      score += sigmoidf_(x) * w3_s[j];
    }
    if (hq == 0 && lrow[i] < L_) scores_s[lrow[i]] = score;
  }
  __syncthreads();

  // ---- masked softmax over L ----
  float sval = -INFINITY;
  if (t < L_) {
    int mv = masks[(size_t)b * L_ + t];
    sval = mv ? scores_s[t] : -4294967295.0f;  // NEG_LARGE
  }
  float m = sval;
  #pragma unroll
  for (int o = 32; o > 0; o >>= 1) m = fmaxf(m, __shfl_xor(m, o, 64));
  if (lane == 0) red_s[wave] = m;
  __syncthreads();
  m = fmaxf(fmaxf(red_s[0], red_s[1]), fmaxf(red_s[2], red_s[3]));
  float e = (t < L_) ? __expf(sval - m) : 0.0f;
  float ssum = e;
  #pragma unroll
  for (int o = 32; o > 0; o >>= 1) ssum += __shfl_xor(ssum, o, 64);
  if (lane == 0) red_s[4 + wave] = ssum;
  __syncthreads();
  ssum = red_s[4] + red_s[5] + red_s[6] + red_s[7];
  float attn = e / ssum;
  __syncthreads();            // raw scores fully consumed
  if (t < L_) scores_s[t] = attn;
  __syncthreads();

  // ---- weighted sum: out[d] = sum_l attn[l] * ub[l,d] (coalesced rows, 2-way l split) ----
  {
    int d = t & 127;
    int half = t >> 7;
    float o = 0.0f;
    #pragma unroll 4
    for (int l = half; l < L_; l += 2)
      o += scores_s[l] * ubbase[(size_t)l * D2_ + d];
    wqs[half * 128 + d] = o;   // reuse wqs as scratch
  }
  __syncthreads();
  if (t < 128) out[(size_t)b * 128 + t] = wqs[t] + wqs[128 + t];
}

extern "C" void kernel_launch(void* const* d_in, const int* in_sizes, int n_in,
                              void* d_out, int out_size, void* d_ws, size_t ws_size,
                              hipStream_t stream) {
  const float* queries = (const float*)d_in[0];
  const float* ub      = (const float*)d_in[1];
  const int*   masks   = (const int*)d_in[2];
  const float* w1      = (const float*)d_in[3];
  const float* b1      = (const float*)d_in[4];
  const float* w2      = (const float*)d_in[5];
  const float* b2      = (const float*)d_in[6];
  const float* w3      = (const float*)d_in[7];
  const float* b3      = (const float*)d_in[8];
  float* out = (float*)d_out;

  const int B = in_sizes[0] / D2_;   // 2048
  din_attn_kernel<<<B, 256, 0, stream>>>(queries, ub, masks, w1, b1, w2, b2, w3, b3, out);
}

// Round 2
// 549.504 us; speedup vs baseline: 1.0277x; 1.0277x over previous
//
#include <hip/hip_runtime.h>
#include <cstddef>

// DIN-style attention: per (b,l) MLP score -> masked softmax over L -> weighted sum.
// B=2048, L=200, 2D=128, H1=80, H2=40.
// Algebra: feats=[q,ub,q-ub,q*ub] =>
//   preact1[l,h] = qt[h] + sum_k ub[l,k]*Wq[k,h]
//   qt[h]  = b1[h] + sum_k q[k]*(W1[k,h] + W1[256+k,h])
//   Wq[k,h]= W1[128+k,h] - W1[256+k,h] + q[k]*W1[384+k,h]
// R2: LDS-instruction-bound fix. GEMM1: 8 rows x 10 cols per lane, b128 reads
// of both operands (WqT stored [h][kk]). Layer2: hv roundtrip via bf16 LDS,
// wave=10-col j-group, w2 transposed fp32 -> b128 reads over 4 h. No shuffles.

#define L_   200
#define D2_  128
#define H1_  80
#define H2_  40

#define UB_STRIDE  36   // fp32 dwords per ub row (32 kk + pad)
#define WQT_STRIDE 36   // fp32 dwords per WqT row (32 kk + pad)
#define W2T_STRIDE 84   // fp32 dwords per w2T row (80 h + pad)
#define HV_STRIDE  88   // bf16 units per hv row (80 h + pad, 176B: 8B aligned, odd dword-stride)

__device__ __forceinline__ float sigmoidf_(float x) {
  return 1.0f / (1.0f + __expf(-x));
}

__device__ __forceinline__ unsigned short f2bf_(float x) {
  unsigned int u = __float_as_uint(x);
  u = (u + 0x7fffu + ((u >> 16) & 1u)) >> 16;   // RNE
  return (unsigned short)u;
}

__device__ __forceinline__ float bf2f_(unsigned short s) {
  return __uint_as_float(((unsigned int)s) << 16);
}

extern "C" __global__ void __launch_bounds__(256, 2)
din_attn_kernel(const float* __restrict__ queries,
                const float* __restrict__ ub,
                const int*   __restrict__ masks,
                const float* __restrict__ w1,
                const float* __restrict__ b1,
                const float* __restrict__ w2,
                const float* __restrict__ b2,
                const float* __restrict__ w3,
                const float* __restrict__ b3,
                float* __restrict__ out)
{
  __shared__ __align__(16) float q_s[128];
  __shared__ __align__(16) float qt_s[H1_];
  __shared__ __align__(16) float w2t_s[H2_ * W2T_STRIDE];  // 13.44 KB, [j][h]
  __shared__ __align__(16) float b2_s[H2_];
  __shared__ __align__(16) float w3_s[H2_];
  __shared__ float b3_s;
  // pool: phase1 = ubs (200x36 f32, 28.8KB) + wqst (80x36 f32, 11.52KB) = 40.32KB
  //       phase2 = hv (200x88 bf16, 35.2KB)
  __shared__ __align__(16) char pool[40320];
  __shared__ __align__(16) float scores_s[256];
  __shared__ __align__(16) float scratch[1088];  // qt partials(240) / scorep(4x208) / wsum(8x136)
  __shared__ float red_s[8];

  float* ubs  = (float*)pool;
  float* wqst = (float*)(pool + 28800);
  unsigned short* hv = (unsigned short*)pool;

  const int b    = blockIdx.x;
  const int t    = threadIdx.x;
  const int wave = t >> 6;
  const int lane = t & 63;
  const int li   = lane & 7;       // row sub-index 0..7
  const int hq   = lane >> 3;      // 0..7
  const int h0   = hq * 10;

  // ---- stage q ----
  if (t < 128) q_s[t] = queries[(size_t)b * D2_ + t];
  __syncthreads();

  // ---- qt partials into scratch; stage w2T/b2/w3/b3 ----
  if (t < 240) {
    const int h = t % 80, seg = t / 80;
    const int k0 = seg * 43;
    const int k1 = (k0 + 43 < 128) ? (k0 + 43) : 128;
    float acc = 0.0f;
    for (int k = k0; k < k1; ++k)
      acc += q_s[k] * (w1[k * H1_ + h] + w1[(256 + k) * H1_ + h]);
    scratch[seg * 80 + h] = acc;
  }
  #pragma unroll
  for (int i = 0; i < 13; ++i) {
    int idx = i * 256 + t;
    if (idx < H1_ * H2_) {
      int h = idx / 40, j = idx - h * 40;
      w2t_s[j * W2T_STRIDE + h] = w2[idx];
    }
  }
  if (t < 40) b2_s[t] = b2[t];
  if (t >= 64 && t < 104) w3_s[t - 64] = w3[t - 64];
  if (t == 128) b3_s = b3[0];
  __syncthreads();
  if (t < 80) qt_s[t] = b1[t] + scratch[t] + scratch[80 + t] + scratch[160 + t];
  __syncthreads();

  // ---- GEMM1: (200x128)@(128x80); rows: l = wave*64 + i*8 + li, cols h0..h0+9 ----
  int ro[8];
  #pragma unroll
  for (int i = 0; i < 8; ++i) {
    int l = wave * 64 + i * 8 + li;
    ro[i] = (l < L_ ? l : L_ - 1) * UB_STRIDE;
  }

  float a[8][10];
  #pragma unroll
  for (int i = 0; i < 8; ++i)
    #pragma unroll
    for (int c = 0; c < 10; ++c) a[i][c] = 0.0f;

  const float* ubbase = ub + (size_t)b * L_ * D2_;
  const float4* ub4base = (const float4*)ubbase;

  for (int kc = 0; kc < 4; ++kc) {
    // stage ub chunk as float4 (1600 float4 slots)
    #pragma unroll
    for (int i = 0; i < 7; ++i) {
      int idx = i * 256 + t;
      if (idx < 1600) {
        int l = idx >> 3, c = idx & 7;
        float4 v = ub4base[l * 32 + kc * 8 + c];
        *(float4*)(ubs + l * UB_STRIDE + c * 4) = v;
      }
    }
    // build WqT chunk: wqst[h][kk] (2560 elems)
    #pragma unroll
    for (int i = 0; i < 10; ++i) {
      int idx = i * 256 + t;
      int kk = idx / 80, h = idx - kk * 80;
      int k = kc * 32 + kk;
      wqst[h * WQT_STRIDE + kk] = w1[(128 + k) * H1_ + h] - w1[(256 + k) * H1_ + h]
                                + q_s[k] * w1[(384 + k) * H1_ + h];
    }
    __syncthreads();

    #pragma unroll 2
    for (int kk = 0; kk < 32; kk += 4) {
      float4 u[8];
      #pragma unroll
      for (int i = 0; i < 8; ++i) u[i] = *(const float4*)(ubs + ro[i] + kk);
      #pragma unroll
      for (int c = 0; c < 10; ++c) {
        float4 wv = *(const float4*)(wqst + (h0 + c) * WQT_STRIDE + kk);
        #pragma unroll
        for (int i = 0; i < 8; ++i) {
          a[i][c] += u[i].x * wv.x;
          a[i][c] += u[i].y * wv.y;
          a[i][c] += u[i].z * wv.z;
          a[i][c] += u[i].w * wv.w;
        }
      }
    }
    __syncthreads();
  }

  // ---- hv = sigmoid(preact1) -> bf16 LDS (aliases ubs/wqst) ----
  #pragma unroll
  for (int i = 0; i < 8; ++i) {
    int l = wave * 64 + i * 8 + li;
    if (l < L_) {
      #pragma unroll
      for (int c2 = 0; c2 < 5; ++c2) {
        float v0 = sigmoidf_(a[i][2 * c2]     + qt_s[h0 + 2 * c2]);
        float v1 = sigmoidf_(a[i][2 * c2 + 1] + qt_s[h0 + 2 * c2 + 1]);
        unsigned int pk = (unsigned int)f2bf_(v0) | ((unsigned int)f2bf_(v1) << 16);
        *(unsigned int*)(hv + l * HV_STRIDE + h0 + 2 * c2) = pk;
      }
    }
  }
  __syncthreads();

  // ---- layer2+3: wave=j-group (10 cols), lane=row-base (4 rows) ----
  {
    const int j0 = wave * 10;
    int rl[4], valid[4];
    #pragma unroll
    for (int i = 0; i < 4; ++i) {
      int l = lane + 64 * i;
      valid[i] = (l < L_);
      rl[i] = (l < L_ ? l : L_ - 1);
    }
    float p[4][10];
    #pragma unroll
    for (int i = 0; i < 4; ++i)
      #pragma unroll
      for (int jj = 0; jj < 10; ++jj) p[i][jj] = 0.0f;

    for (int h = 0; h < 80; h += 4) {
      float hf[4][4];
      #pragma unroll
      for (int i = 0; i < 4; ++i) {
        ushort4 hb = *(const ushort4*)(hv + rl[i] * HV_STRIDE + h);
        hf[i][0] = bf2f_(hb.x); hf[i][1] = bf2f_(hb.y);
        hf[i][2] = bf2f_(hb.z); hf[i][3] = bf2f_(hb.w);
      }
      #pragma unroll
      for (int jj = 0; jj < 10; ++jj) {
        float4 wv = *(const float4*)(w2t_s + (j0 + jj) * W2T_STRIDE + h);
        #pragma unroll
        for (int i = 0; i < 4; ++i) {
          p[i][jj] += hf[i][0] * wv.x;
          p[i][jj] += hf[i][1] * wv.y;
          p[i][jj] += hf[i][2] * wv.z;
          p[i][jj] += hf[i][3] * wv.w;
        }
      }
    }
    #pragma unroll
    for (int i = 0; i < 4; ++i) {
      float s = 0.0f;
      #pragma unroll
      for (int jj = 0; jj < 10; ++jj)
        s += sigmoidf_(p[i][jj] + b2_s[j0 + jj]) * w3_s[j0 + jj];
      if (valid[i]) scratch[wave * 208 + rl[i]] = s;
    }
  }
  __syncthreads();

  // ---- masked softmax over L ----
  float sval = -INFINITY;
  if (t < L_) {
    float sc = scratch[t] + scratch[208 + t] + scratch[416 + t] + scratch[624 + t] + b3_s;
    int mv = masks[(size_t)b * L_ + t];
    sval = mv ? sc : -4294967295.0f;  // NEG_LARGE
  }
  float m = sval;
  #pragma unroll
  for (int o = 32; o > 0; o >>= 1) m = fmaxf(m, __shfl_xor(m, o, 64));
  if (lane == 0) red_s[wave] = m;
  __syncthreads();
  m = fmaxf(fmaxf(red_s[0], red_s[1]), fmaxf(red_s[2], red_s[3]));
  float e = (t < L_) ? __expf(sval - m) : 0.0f;
  float ssum = e;
  #pragma unroll
  for (int o = 32; o > 0; o >>= 1) ssum += __shfl_xor(ssum, o, 64);
  if (lane == 0) red_s[4 + wave] = ssum;
  __syncthreads();
  ssum = red_s[4] + red_s[5] + red_s[6] + red_s[7];
  float attn = e / ssum;
  __syncthreads();            // scratch (scorep) fully consumed
  if (t < L_) scores_s[t] = attn;
  __syncthreads();

  // ---- weighted sum: float4 over d, 8-way split over l ----
  {
    int d4 = t & 31;
    int lg = t >> 5;
    float4 o = make_float4(0.f, 0.f, 0.f, 0.f);
    #pragma unroll 5
    for (int l = lg; l < L_; l += 8) {
      float w = scores_s[l];
      float4 v = ub4base[l * 32 + d4];
      o.x += w * v.x; o.y += w * v.y; o.z += w * v.z; o.w += w * v.w;
    }
    *(float4*)(scratch + lg * 136 + d4 * 4) = o;
  }
  __syncthreads();
  if (t < 128) {
    float s = 0.0f;
    #pragma unroll
    for (int lg = 0; lg < 8; ++lg) s += scratch[lg * 136 + t];
    out[(size_t)b * 128 + t] = s;
  }
}

extern "C" void kernel_launch(void* const* d_in, const int* in_sizes, int n_in,
                              void* d_out, int out_size, void* d_ws, size_t ws_size,
                              hipStream_t stream) {
  const float* queries = (const float*)d_in[0];
  const float* ub      = (const float*)d_in[1];
  const int*   masks   = (const int*)d_in[2];
  const float* w1      = (const float*)d_in[3];
  const float* b1      = (const float*)d_in[4];
  const float* w2      = (const float*)d_in[5];
  const float* b2      = (const float*)d_in[6];
  const float* w3      = (const float*)d_in[7];
  const float* b3      = (const float*)d_in[8];
  float* out = (float*)d_out;

  const int B = in_sizes[0] / D2_;   // 2048
  din_attn_kernel<<<B, 256, 0, stream>>>(queries, ub, masks, w1, b1, w2, b2, w3, b3, out);
}

// Round 4
// 391.180 us; speedup vs baseline: 1.4436x; 1.4047x over previous
//
#include <hip/hip_runtime.h>
#include <cstddef>

// DIN attention, R4: MFMA, single kernel (no d_ws), defensive LDS hygiene.
// preact1[l,h] = qt[h] + sum_k ub[l,k]*Wq[k,h]
//   qt[h]  = b1[h] + sum_k q[k]*(W1[k,h]+W1[256+k,h])
//   Wq[k,h]= W1[128+k,h] - W1[256+k,h] + q[k]*W1[384+k,h]
// GEMM1: 13x5 tiles of 16x16x32 bf16 MFMA, K=128 (4 ksteps).
// layer2: 13x3 tiles, K=80 padded to 96; BOTH A-pad (hv kg 10,11) and B-pad zeroed.
// LDS fragments packed as contiguous 16B slots: lane reads base+lane (conflict-free).

#define L_   200
#define D2_  128

typedef __attribute__((ext_vector_type(8))) short bf16x8;
typedef __attribute__((ext_vector_type(4))) float f32x4;
typedef __attribute__((ext_vector_type(4))) unsigned int u32x4;

__device__ __forceinline__ float sigmoidf_(float x) { return 1.0f / (1.0f + __expf(-x)); }

__device__ __forceinline__ unsigned int f2bf_(float x) {
  unsigned int u = __float_as_uint(x);
  return (u + 0x7fffu + ((u >> 16) & 1u)) >> 16;   // RNE, low 16 bits valid
}
__device__ __forceinline__ unsigned int pk2_(float a, float b) {
  return f2bf_(a) | (f2bf_(b) << 16);
}

extern "C" __global__ void __launch_bounds__(256, 3)
din_attn_kernel(const float* __restrict__ queries,
                const float* __restrict__ ub,
                const int*   __restrict__ masks,
                const float* __restrict__ w1,
                const float* __restrict__ b1,
                const float* __restrict__ w2,
                const float* __restrict__ b2,
                const float* __restrict__ w3,
                float* __restrict__ out)
{
  // pool: GEMM1 phase = A-chunk (832 slots, 13312B) + Bwq (1280 slots, 20480B)
  //       layer2 phase = hv A-frags (13*12*16 = 2496 slots, 39936B) — ALL slots written
  //       final phase  = wsum scratch (fp32)
  __shared__ __align__(16) char pool[39936];
  __shared__ __align__(16) char w2f[9216];      // 3*12*16 = 576 slots
  __shared__ __align__(16) float q_s[128];
  __shared__ __align__(16) float qt_s[80];
  __shared__ __align__(16) float b2_s[48];
  __shared__ __align__(16) float w3_s[48];
  __shared__ __align__(16) float scores_s[208];
  __shared__ float red_s[8];

  const int b    = blockIdx.x;
  const int t    = threadIdx.x;
  const int wave = t >> 6;
  const int lane = t & 63;

  const float* ubbase = ub + (size_t)b * L_ * D2_;
  const float4* ub4base = (const float4*)ubbase;

  // ---- stage q, b2, w3 ----
  if (t < 128) q_s[t] = queries[(size_t)b * D2_ + t];
  if (t < 48) {
    b2_s[t] = (t < 40) ? b2[t] : 0.0f;
    w3_s[t] = (t < 40) ? w3[t] : 0.0f;
  }
  __syncthreads();

  // ---- qt[h] = b1[h] + sum_k q[k]*(W1a+W1c)[k,h]  (w1 is L2-resident) ----
  if (t < 80) {
    float acc = b1[t];
    #pragma unroll 4
    for (int k = 0; k < 128; ++k)
      acc += q_s[k] * (w1[k * 80 + t] + w1[(256 + k) * 80 + t]);
    qt_s[t] = acc;
  }

  // ---- build Bwq frags: slot s=((kc*5+nt)*4+kg)*16+n holds Wq[k0..k0+7][h], bf16 ----
  {
    u32x4* dst = (u32x4*)(pool + 13312);
    #pragma unroll
    for (int i = 0; i < 5; ++i) {
      int s = i * 256 + t;                 // 0..1279
      int n = s & 15, kg = (s >> 4) & 3, g = s >> 6;
      int kc = g / 5, nt = g - kc * 5;
      int h = nt * 16 + n, k0 = kc * 32 + kg * 8;
      float wv[8];
      #pragma unroll
      for (int j = 0; j < 8; ++j) {
        int k = k0 + j;
        wv[j] = w1[(128 + k) * 80 + h] - w1[(256 + k) * 80 + h]
              + q_s[k] * w1[(384 + k) * 80 + h];
      }
      u32x4 v = { pk2_(wv[0], wv[1]), pk2_(wv[2], wv[3]),
                  pk2_(wv[4], wv[5]), pk2_(wv[6], wv[7]) };
      dst[s] = v;
    }
  }

  // ---- build w2 B-frags: slot s=(nt2*12+kg)*16+n holds w2[k0..k0+7][j], pads zero ----
  {
    u32x4* dst = (u32x4*)w2f;
    #pragma unroll
    for (int i = 0; i < 3; ++i) {
      int s = i * 256 + t;
      if (s < 576) {
        int n = s & 15, g = s >> 4;
        int nt2 = g / 12, kg = g - nt2 * 12;
        int j = nt2 * 16 + n;
        u32x4 v = { 0u, 0u, 0u, 0u };
        if (j < 40 && kg < 10) {
          int k0 = kg * 8;
          float e0 = w2[(k0 + 0) * 40 + j], e1 = w2[(k0 + 1) * 40 + j];
          float e2 = w2[(k0 + 2) * 40 + j], e3 = w2[(k0 + 3) * 40 + j];
          float e4 = w2[(k0 + 4) * 40 + j], e5 = w2[(k0 + 5) * 40 + j];
          float e6 = w2[(k0 + 6) * 40 + j], e7 = w2[(k0 + 7) * 40 + j];
          v = (u32x4){ pk2_(e0, e1), pk2_(e2, e3), pk2_(e4, e5), pk2_(e6, e7) };
        }
        dst[s] = v;
      }
    }
  }

  // ---- GEMM1: C[l,h], 65 tiles over 4 waves, 4 ksteps of 32 ----
  f32x4 acc[17];
  #pragma unroll
  for (int i = 0; i < 17; ++i) acc[i] = (f32x4){0.f, 0.f, 0.f, 0.f};

  const bf16x8* Af = (const bf16x8*)pool;
  const bf16x8* Bf = (const bf16x8*)(pool + 13312);

  for (int kc = 0; kc < 4; ++kc) {
    // stage A chunk: slot s=(mt*4+kg)*16+m holds ub_bf16[l=mt*16+m][kc*32+kg*8 ..+7]
    u32x4* dst = (u32x4*)pool;
    #pragma unroll
    for (int i = 0; i < 4; ++i) {
      int s = i * 256 + t;
      if (s < 832) {
        int m = s & 15, kg = (s >> 4) & 3, mt = s >> 6;
        int l = mt * 16 + m;
        u32x4 v = { 0u, 0u, 0u, 0u };
        if (l < L_) {
          const float4* src = (const float4*)(ubbase + (size_t)l * D2_ + kc * 32 + kg * 8);
          float4 u0 = src[0], u1 = src[1];
          v = (u32x4){ pk2_(u0.x, u0.y), pk2_(u0.z, u0.w), pk2_(u1.x, u1.y), pk2_(u1.z, u1.w) };
        }
        dst[s] = v;
      }
    }
    __syncthreads();

    #pragma unroll
    for (int i = 0; i < 17; ++i) {
      int tt = i * 4 + wave;
      if (tt < 65) {
        int mt = tt / 5, nt = tt - mt * 5;
        bf16x8 av = Af[mt * 64 + lane];
        bf16x8 bv = Bf[(kc * 5 + nt) * 64 + lane];
        acc[i] = __builtin_amdgcn_mfma_f32_16x16x32_bf16(av, bv, acc[i], 0, 0, 0);
      }
    }
    __syncthreads();
  }

  // ---- epilogue1: hv = sigmoid(preact1) -> A-frag layout; zero kg 10,11 pad slots ----
  {
    // zero the layer2 K-pad A-slots (k=80..95): slots (mt*12+10)*16 .. +31, 13*32=416 slots
    u32x4* pz = (u32x4*)pool;
    #pragma unroll
    for (int s = 0; s < 2; ++s) {
      int idx = s * 256 + t;
      if (idx < 416) {
        int mt = idx >> 5, off = idx & 31;
        pz[(mt * 12 + 10) * 16 + off] = (u32x4){ 0u, 0u, 0u, 0u };
      }
    }
    unsigned short* hv = (unsigned short*)pool;
    const int n = lane & 15, rg = lane >> 4;
    #pragma unroll
    for (int i = 0; i < 17; ++i) {
      int tt = i * 4 + wave;
      if (tt < 65) {
        int mt = tt / 5, nt = tt - mt * 5;
        int h = nt * 16 + n;
        int kg = h >> 3, hb = h & 7;
        float qtv = qt_s[h];
        #pragma unroll
        for (int r = 0; r < 4; ++r) {
          float x = acc[i][r] + qtv;
          hv[((mt * 12 + kg) * 16 + rg * 4 + r) * 8 + hb] = (unsigned short)f2bf_(sigmoidf_(x));
        }
      }
    }
  }
  __syncthreads();

  // ---- layer2: C2[l,j], 13x3 tiles, K=96 (A pads zeroed, B pads zeroed) ----
  f32x4 acc2[4][3];
  #pragma unroll
  for (int i = 0; i < 4; ++i)
    #pragma unroll
    for (int n2 = 0; n2 < 3; ++n2) acc2[i][n2] = (f32x4){0.f, 0.f, 0.f, 0.f};

  {
    const bf16x8* hvf = (const bf16x8*)pool;
    const bf16x8* w2ff = (const bf16x8*)w2f;
    #pragma unroll
    for (int i = 0; i < 4; ++i) {
      int mt = wave + i * 4;
      if (mt < 13) {
        #pragma unroll
        for (int ks = 0; ks < 3; ++ks) {
          bf16x8 av = hvf[mt * 192 + ks * 64 + lane];
          #pragma unroll
          for (int n2 = 0; n2 < 3; ++n2) {
            bf16x8 bv = w2ff[n2 * 192 + ks * 64 + lane];
            acc2[i][n2] = __builtin_amdgcn_mfma_f32_16x16x32_bf16(av, bv, acc2[i][n2], 0, 0, 0);
          }
        }
      }
    }
  }

  // ---- epilogue2: score_l = sum_j sigmoid(p2+b2[j])*w3[j]; reduce over 16 cols ----
  {
    const int n = lane & 15, rg = lane >> 4;
    #pragma unroll
    for (int i = 0; i < 4; ++i) {
      int mt = wave + i * 4;
      if (mt < 13) {
        #pragma unroll
        for (int r = 0; r < 4; ++r) {
          float s = 0.0f;
          #pragma unroll
          for (int n2 = 0; n2 < 3; ++n2) {
            int j = n2 * 16 + n;
            s += sigmoidf_(acc2[i][n2][r] + b2_s[j]) * w3_s[j];
          }
          s += __shfl_xor(s, 1, 64);
          s += __shfl_xor(s, 2, 64);
          s += __shfl_xor(s, 4, 64);
          s += __shfl_xor(s, 8, 64);
          int l = mt * 16 + rg * 4 + r;
          if (n == 0 && l < L_) scores_s[l] = s;
        }
      }
    }
  }
  __syncthreads();

  // ---- masked softmax over L (b3 omitted: softmax shift-invariant) ----
  float sval = -INFINITY;
  if (t < L_) {
    int mv = masks[(size_t)b * L_ + t];
    sval = mv ? scores_s[t] : -4294967295.0f;  // NEG_LARGE
  }
  float m = sval;
  #pragma unroll
  for (int o = 32; o > 0; o >>= 1) m = fmaxf(m, __shfl_xor(m, o, 64));
  if (lane == 0) red_s[wave] = m;
  __syncthreads();
  m = fmaxf(fmaxf(red_s[0], red_s[1]), fmaxf(red_s[2], red_s[3]));
  float e = (t < L_) ? __expf(sval - m) : 0.0f;
  float ssum = e;
  #pragma unroll
  for (int o = 32; o > 0; o >>= 1) ssum += __shfl_xor(ssum, o, 64);
  if (lane == 0) red_s[4 + wave] = ssum;
  __syncthreads();
  ssum = red_s[4] + red_s[5] + red_s[6] + red_s[7];
  float attn = e / ssum;
  __syncthreads();
  if (t < L_) scores_s[t] = attn;
  __syncthreads();

  // ---- weighted sum: out[d] = sum_l attn[l]*ub[l,d] (fp32, float4, 8-way l split) ----
  {
    float* wsum = (float*)pool;
    int d4 = t & 31;
    int lg = t >> 5;
    float4 o = make_float4(0.f, 0.f, 0.f, 0.f);
    #pragma unroll 5
    for (int l = lg; l < L_; l += 8) {
      float w = scores_s[l];
      float4 v = ub4base[l * 32 + d4];
      o.x += w * v.x; o.y += w * v.y; o.z += w * v.z; o.w += w * v.w;
    }
    *(float4*)(wsum + lg * 136 + d4 * 4) = o;
    __syncthreads();
    if (t < 128) {
      float s = 0.0f;
      #pragma unroll
      for (int g = 0; g < 8; ++g) s += wsum[g * 136 + t];
      out[(size_t)b * 128 + t] = s;
    }
  }
}

extern "C" void kernel_launch(void* const* d_in, const int* in_sizes, int n_in,
                              void* d_out, int out_size, void* d_ws, size_t ws_size,
                              hipStream_t stream) {
  const float* queries = (const float*)d_in[0];
  const float* ub      = (const float*)d_in[1];
  const int*   masks   = (const int*)d_in[2];
  const float* w1      = (const float*)d_in[3];
  const float* b1      = (const float*)d_in[4];
  const float* w2      = (const float*)d_in[5];
  const float* b2      = (const float*)d_in[6];
  const float* w3      = (const float*)d_in[7];
  float* out = (float*)d_out;

  const int B = in_sizes[0] / D2_;   // 2048
  din_attn_kernel<<<B, 256, 0, stream>>>(queries, ub, masks, w1, b1, w2, b2, w3, out);
}